// Round 13
// baseline (198.267 us; speedup 1.0000x reference)
//
#include <hip/hip_runtime.h>

// 2-layer LSTM, B=4096, S=512, F=8, H=10 + FC(10->1) on last step.
// R12: fused both-layers-in-one-wave (R11 structure: L1 lags L0 by 1 step,
// h0 handoff = previous iteration's register readback, ZERO barriers,
// uniform 512x256 grid = 2 blocks/CU) + R10's PROVEN gate micro-scheme
// verbatim (R11's single-bperm rewiring failed; isolate that variable):
//   all 20 lanes compute (rA=l20, rB=20+l20) gate pair; unified act
//   alpha*rcp(1+exp2(-a))+beta; ig local on i/g lanes; sf,so pulled from
//   lane+10 via 2 bperms; c/h update on i/g lanes; h row write h0r[l20].
// Wave = 2 elements at 32-lane stride (lanes 20-31 of each group idle).

typedef __fp16 v2h __attribute__((ext_vector_type(2)));
typedef __fp16 v8h __attribute__((ext_vector_type(8)));
struct h4 { v2h a, b, c, d; };

#define L2E 1.4426950408889634f

__device__ __forceinline__ v2h pkh(float a, float b) {
    return __builtin_amdgcn_cvt_pkrtz(a, b);
}
__device__ __forceinline__ float bpermf(int baddr, float v) {
    int r = __builtin_amdgcn_ds_bpermute(baddr, __builtin_bit_cast(int, v));
    return __builtin_bit_cast(float, r);
}

#define SIGM(a)  __builtin_amdgcn_rcpf(1.0f + __builtin_amdgcn_exp2f(-(a)))
#define TANHP(a) fmaf(-2.0f, __builtin_amdgcn_rcpf(1.0f + __builtin_amdgcn_exp2f(a)), 1.0f)
#define DOT2(acc, w, v) (acc) = __builtin_amdgcn_fdot2((w), (v), (acc), false)

// TBAA-safe packed row read (PTR __fp16*, 16B aligned): 10 halves
#define READROW(PTR, H)                                                      \
    { v8h w0_ = *(const v8h*)(PTR);                                          \
      v2h w1_ = *(const v2h*)((PTR) + 8);                                    \
      h4 q_ = __builtin_bit_cast(h4, w0_);                                   \
      H[0]=q_.a; H[1]=q_.b; H[2]=q_.c; H[3]=q_.d; H[4]=w1_; }

__global__ __launch_bounds__(256, 2)
void lstm2_r12(const float* __restrict__ x,
               const float* __restrict__ hid,
               const float* __restrict__ cel,
               const float* __restrict__ Wih0, const float* __restrict__ Whh0,
               const float* __restrict__ bih0, const float* __restrict__ bhh0,
               const float* __restrict__ Wih1, const float* __restrict__ Whh1,
               const float* __restrict__ bih1, const float* __restrict__ bhh1,
               const float* __restrict__ Wfc,  const float* __restrict__ bfc,
               float* __restrict__ out)
{
    __shared__ __attribute__((aligned(16))) __fp16 hrow[4][2][2][24]; // [wave][elem][layer][24]
    __shared__ float fcb[8][10];

    const int tid  = threadIdx.x;
    const int lane = tid & 63;
    const int wid  = tid >> 6;
    const int sub  = lane & 31;          // lane within 32-group
    const int grp  = lane >> 5;          // element within wave (0,1)
    const int l20  = (sub < 20) ? sub : 19;
    const bool unit = (sub < 10);                      // i/g lanes: own c/h (R10 scheme)
    const int  ju  = (l20 >= 10) ? l20 - 10 : l20;     // unit index
    const int  eIB = wid * 2 + grp;      // element in block, 0..7
    const int  e   = blockIdx.x * 8 + eIB;             // 512*8 = 4096 exact
    const int  baddr = (unit ? (lane + 10) : lane) * 4;  // sf/so source (R10)

    const float alpha2 = (l20 < 10) ? 2.0f : 1.0f;     // rowB act: tanh vs sigma
    const float beta2  = (l20 < 10) ? -1.0f : 0.0f;
    const float scB    = (l20 < 10) ? 2.0f * L2E : L2E;
    const int   rA = l20, rB = 20 + l20;

    // ---- register weights, both layers ----
    v2h wxA[4], wxB[4], whA0[5], whB0[5];
    v2h wiA[5], wiB[5], whA1[5], whB1[5];
    #pragma unroll
    for (int k = 0; k < 4; ++k) {
        wxA[k] = pkh(Wih0[rA*8+2*k]*L2E, Wih0[rA*8+2*k+1]*L2E);
        wxB[k] = pkh(Wih0[rB*8+2*k]*scB, Wih0[rB*8+2*k+1]*scB);
    }
    #pragma unroll
    for (int k = 0; k < 5; ++k) {
        whA0[k] = pkh(Whh0[rA*10+2*k]*L2E, Whh0[rA*10+2*k+1]*L2E);
        whB0[k] = pkh(Whh0[rB*10+2*k]*scB, Whh0[rB*10+2*k+1]*scB);
        wiA[k]  = pkh(Wih1[rA*10+2*k]*L2E, Wih1[rA*10+2*k+1]*L2E);
        wiB[k]  = pkh(Wih1[rB*10+2*k]*scB, Wih1[rB*10+2*k+1]*scB);
        whA1[k] = pkh(Whh1[rA*10+2*k]*L2E, Whh1[rA*10+2*k+1]*L2E);
        whB1[k] = pkh(Whh1[rB*10+2*k]*scB, Whh1[rB*10+2*k+1]*scB);
    }
    const float bA0 = (bih0[rA] + bhh0[rA]) * L2E;
    const float bB0 = (bih0[rB] + bhh0[rB]) * scB;
    const float bA1 = (bih1[rA] + bhh1[rA]) * L2E;
    const float bB1 = (bih1[rB] + bhh1[rB]) * scB;
    const float wfc = Wfc[ju];

    // ---- state (meaningful on unit lanes; others compute dead values) ----
    v2h hv0[5], hv1[5];
    #pragma unroll
    for (int k = 0; k < 5; ++k) {
        hv0[k] = pkh(hid[e*10+2*k],         hid[e*10+2*k+1]);
        hv1[k] = pkh(hid[40960+e*10+2*k],   hid[40960+e*10+2*k+1]);
    }
    float cc0 = cel[e*10 + ju];
    float cc1 = cel[40960 + e*10 + ju];
    float hj0 = 0.0f, hj1 = 0.0f;

    __fp16* const h0r = &hrow[wid][grp][0][0];
    __fp16* const h1r = &hrow[wid][grp][1][0];

    const float4* __restrict__ xp4 = reinterpret_cast<const float4*>(x + (size_t)e * 4096);
    float4 xa[2], xb[2], xc[2], xd[2];           // x[t] at xp4[2t], xp4[2t+1]
    xa[0]=xp4[0]; xa[1]=xp4[1];  xb[0]=xp4[2]; xb[1]=xp4[3];
    xc[0]=xp4[4]; xc[1]=xp4[5];  xd[0]=xp4[6]; xd[1]=xp4[7];

// One fused body: L0 step s (buffer XB = x[s]) + L1 step s-1 (R10 micro-
// scheme both). L1 input = hv0 (= h0[s-1] here), L1 recurrent = hv1.
#define BODY(XB, RPTR, DO_REF, DO_L1)                                        \
    {                                                                        \
        v2h x0=pkh(XB[0].x,XB[0].y), x1=pkh(XB[0].z,XB[0].w);                \
        v2h x2=pkh(XB[1].x,XB[1].y), x3=pkh(XB[1].z,XB[1].w);                \
        if (DO_REF) { XB[0]=(RPTR)[0]; XB[1]=(RPTR)[1]; }                    \
        float aA0=bA0, aB0=bB0;                                              \
        DOT2(aA0,wxA[0],x0); DOT2(aB0,wxB[0],x0);                            \
        DOT2(aA0,wxA[1],x1); DOT2(aB0,wxB[1],x1);                            \
        DOT2(aA0,wxA[2],x2); DOT2(aB0,wxB[2],x2);                            \
        DOT2(aA0,wxA[3],x3); DOT2(aB0,wxB[3],x3);                            \
        DOT2(aA0,whA0[0],hv0[0]); DOT2(aB0,whB0[0],hv0[0]);                  \
        DOT2(aA0,whA0[1],hv0[1]); DOT2(aB0,whB0[1],hv0[1]);                  \
        DOT2(aA0,whA0[2],hv0[2]); DOT2(aB0,whB0[2],hv0[2]);                  \
        DOT2(aA0,whA0[3],hv0[3]); DOT2(aB0,whB0[3],hv0[3]);                  \
        DOT2(aA0,whA0[4],hv0[4]); DOT2(aB0,whB0[4],hv0[4]);                  \
        float r1_0 = SIGM(aA0);                                              \
        float r2_0 = SIGM(aB0);                                              \
        float act2_0 = fmaf(alpha2, r2_0, beta2);                            \
        float ig_0 = r1_0 * act2_0;                                          \
        float sf_0 = bpermf(baddr, r1_0);                                    \
        float so_0 = bpermf(baddr, act2_0);                                  \
        if (DO_L1) {                                                         \
            float aA1=bA1, aB1=bB1;                                          \
            DOT2(aA1,wiA[0],hv0[0]); DOT2(aB1,wiB[0],hv0[0]);                \
            DOT2(aA1,wiA[1],hv0[1]); DOT2(aB1,wiB[1],hv0[1]);                \
            DOT2(aA1,wiA[2],hv0[2]); DOT2(aB1,wiB[2],hv0[2]);                \
            DOT2(aA1,wiA[3],hv0[3]); DOT2(aB1,wiB[3],hv0[3]);                \
            DOT2(aA1,wiA[4],hv0[4]); DOT2(aB1,wiB[4],hv0[4]);                \
            DOT2(aA1,whA1[0],hv1[0]); DOT2(aB1,whB1[0],hv1[0]);              \
            DOT2(aA1,whA1[1],hv1[1]); DOT2(aB1,whB1[1],hv1[1]);              \
            DOT2(aA1,whA1[2],hv1[2]); DOT2(aB1,whB1[2],hv1[2]);              \
            DOT2(aA1,whA1[3],hv1[3]); DOT2(aB1,whB1[3],hv1[3]);              \
            DOT2(aA1,whA1[4],hv1[4]); DOT2(aB1,whB1[4],hv1[4]);              \
            float r1_1 = SIGM(aA1);                                          \
            float r2_1 = SIGM(aB1);                                          \
            float act2_1 = fmaf(alpha2, r2_1, beta2);                        \
            float ig_1 = r1_1 * act2_1;                                      \
            float sf_1 = bpermf(baddr, r1_1);                                \
            float so_1 = bpermf(baddr, act2_1);                              \
            cc1 = fmaf(sf_1, cc1, ig_1);                                     \
            hj1 = so_1 * TANHP((2.0f*L2E) * cc1);                            \
            h1r[l20] = (__fp16)hj1;                                          \
        }                                                                    \
        cc0 = fmaf(sf_0, cc0, ig_0);                                         \
        hj0 = so_0 * TANHP((2.0f*L2E) * cc0);                                \
        h0r[l20] = (__fp16)hj0;                                              \
        READROW(h0r, hv0)                                                    \
        if (DO_L1) READROW(h1r, hv1)                                         \
    }

    // s = 0 (no L1); refill xa <- x[4]
    BODY(xa, xp4 + 8, 1, 0)
    // s = 1..504 (126 iters x 4); L1 steps 0..503
    for (int i = 0; i < 126; ++i) {
        const float4* xr = xp4 + 8*i;
        BODY(xb, xr + 10, 1, 1)      // s=4i+1, refill x[4i+5]
        BODY(xc, xr + 12, 1, 1)      // s=4i+2
        BODY(xd, xr + 14, 1, 1)      // s=4i+3
        BODY(xa, xr + 16, 1, 1)      // s=4i+4
    }
    // tail s=505..511
    BODY(xb, xp4 + 1018, 1, 1)       // s=505, refill x[509]
    BODY(xc, xp4 + 1020, 1, 1)       // s=506, refill x[510]
    BODY(xd, xp4 + 1022, 1, 1)       // s=507, refill x[511]
    BODY(xa, xp4, 0, 1)              // s=508
    BODY(xb, xp4, 0, 1)              // s=509
    BODY(xc, xp4, 0, 1)              // s=510
    BODY(xd, xp4, 0, 1)              // s=511
#undef BODY

    // epilogue: L1 step 511 (inputs hv0 = h0[511], hv1 = h1[510])
    {
        float aA1=bA1, aB1=bB1;
        DOT2(aA1,wiA[0],hv0[0]); DOT2(aB1,wiB[0],hv0[0]);
        DOT2(aA1,wiA[1],hv0[1]); DOT2(aB1,wiB[1],hv0[1]);
        DOT2(aA1,wiA[2],hv0[2]); DOT2(aB1,wiB[2],hv0[2]);
        DOT2(aA1,wiA[3],hv0[3]); DOT2(aB1,wiB[3],hv0[3]);
        DOT2(aA1,wiA[4],hv0[4]); DOT2(aB1,wiB[4],hv0[4]);
        DOT2(aA1,whA1[0],hv1[0]); DOT2(aB1,whB1[0],hv1[0]);
        DOT2(aA1,whA1[1],hv1[1]); DOT2(aB1,whB1[1],hv1[1]);
        DOT2(aA1,whA1[2],hv1[2]); DOT2(aB1,whB1[2],hv1[2]);
        DOT2(aA1,whA1[3],hv1[3]); DOT2(aB1,whB1[3],hv1[3]);
        DOT2(aA1,whA1[4],hv1[4]); DOT2(aB1,whB1[4],hv1[4]);
        float r1_1 = SIGM(aA1);
        float r2_1 = SIGM(aB1);
        float act2_1 = fmaf(alpha2, r2_1, beta2);
        float ig_1 = r1_1 * act2_1;
        float sf_1 = bpermf(baddr, r1_1);
        float so_1 = bpermf(baddr, act2_1);
        cc1 = fmaf(sf_1, cc1, ig_1);
        hj1 = so_1 * TANHP((2.0f*L2E) * cc1);
    }

    // ---- outputs (unit lanes own correct c/h, ju = sub) ----
    if (unit) {
        out[4096           + e * 10 + ju] = hj0;   // h0_T
        out[4096 + 81920   + e * 10 + ju] = cc0;   // c0_T
        out[4096 + 40960   + e * 10 + ju] = hj1;   // h1_T
        out[4096 + 122880  + e * 10 + ju] = cc1;   // c1_T
        fcb[eIB][ju] = hj1 * wfc;
    }
    if (sub == 0) {
        float p = bfc[0];
        #pragma unroll
        for (int k = 0; k < 10; ++k) p += fcb[eIB][k];
        out[e] = p;
    }
}

extern "C" void kernel_launch(void* const* d_in, const int* in_sizes, int n_in,
                              void* d_out, int out_size, void* d_ws, size_t ws_size,
                              hipStream_t stream) {
    const float* x    = (const float*)d_in[0];
    const float* hid  = (const float*)d_in[1];
    const float* cel  = (const float*)d_in[2];
    const float* Wih0 = (const float*)d_in[3];
    const float* Whh0 = (const float*)d_in[4];
    const float* bih0 = (const float*)d_in[5];
    const float* bhh0 = (const float*)d_in[6];
    const float* Wih1 = (const float*)d_in[7];
    const float* Whh1 = (const float*)d_in[8];
    const float* bih1 = (const float*)d_in[9];
    const float* bhh1 = (const float*)d_in[10];
    const float* Wfc  = (const float*)d_in[11];
    const float* bfc  = (const float*)d_in[12];

    // 512 blocks x 8 elements = 4096 exact; 2 blocks/CU uniform; no barriers
    hipLaunchKernelGGL(lstm2_r12, dim3(512), dim3(256), 0, stream,
                       x, hid, cel, Wih0, Whh0, bih0, bhh0,
                       Wih1, Whh1, bih1, bhh1, Wfc, bfc,
                       (float*)d_out);
}

// Round 14
// 170.329 us; speedup vs baseline: 1.1640x; 1.1640x over previous
//
#include <hip/hip_runtime.h>

// 2-layer LSTM, B=4096, S=512, F=8, H=10 + FC(10->1) on last step.
// R13: 10-lane element groups — each lane owns ALL 4 gate rows (i,f,g,o)
// of hidden unit j for its element. 6 elements/wave (60/64 lanes).
//  - zero bperm: all gate activations + c/h update lane-local
//  - per-wave glue (x unpack, loop, DS, acts) amortized over 6 elems
//  - 4 independent dot chains/lane (ILP); x-dots first (cover h readback)
//  - producer(L0)/consumer(L1) wave pair per 128-thr block; R10's proven
//    16-slot h0 buffer, 2-phase ping-pong, 64 barriers, lag<=16
//  - h rows 16 halves (32B): readback = ds_read_b128 + b32, TBAA-safe v8h
// 683 blocks x 128 thr = 1366 waves. Weights f16 (L2E/2L2E prescaled),
// accum/act/c f32 (same precision as R10, absmax ~7.8e-3).

typedef __fp16 v2h __attribute__((ext_vector_type(2)));
typedef __fp16 v8h __attribute__((ext_vector_type(8)));
struct h4 { v2h a, b, c, d; };

#define L2E 1.4426950408889634f

__device__ __forceinline__ v2h pkh(float a, float b) {
    return __builtin_amdgcn_cvt_pkrtz(a, b);
}

#define SIGM(a)  __builtin_amdgcn_rcpf(1.0f + __builtin_amdgcn_exp2f(-(a)))
#define TANHP(a) fmaf(-2.0f, __builtin_amdgcn_rcpf(1.0f + __builtin_amdgcn_exp2f(a)), 1.0f)
#define DOT2(acc, w, v) (acc) = __builtin_amdgcn_fdot2((w), (v), (acc), false)

// TBAA-safe packed row read (PTR __fp16*, 16B aligned): 10 halves
#define READROW(PTR, H)                                                      \
    { v8h w0_ = *(const v8h*)(PTR);                                          \
      v2h w1_ = *(const v2h*)((PTR) + 8);                                    \
      h4 q_ = __builtin_bit_cast(h4, w0_);                                   \
      H[0]=q_.a; H[1]=q_.b; H[2]=q_.c; H[3]=q_.d; H[4]=w1_; }

__global__ __launch_bounds__(128, 2)
void lstm2_r13(const float* __restrict__ x,
               const float* __restrict__ hid,
               const float* __restrict__ cel,
               const float* __restrict__ Wih0, const float* __restrict__ Whh0,
               const float* __restrict__ bih0, const float* __restrict__ bhh0,
               const float* __restrict__ Wih1, const float* __restrict__ Whh1,
               const float* __restrict__ bih1, const float* __restrict__ bhh1,
               const float* __restrict__ Wfc,  const float* __restrict__ bfc,
               float* __restrict__ out)
{
    __shared__ __attribute__((aligned(16))) __fp16 h0buf[16][6][16]; // 3 KB
    __shared__ __attribute__((aligned(16))) __fp16 h1buf[6][16];
    __shared__ float fcb[6][10];

    const int tid  = threadIdx.x;
    const int lane = tid & 63;
    const int uwid = __builtin_amdgcn_readfirstlane(tid >> 6);
    int g = lane / 10;                   // element group 0..5
    int j = lane - g * 10;               // hidden unit 0..9
    if (lane >= 60) { g = 5; j = 9; }    // pad lanes duplicate lane 59
    const bool live = (lane < 60);
    const int e  = blockIdx.x * 6 + g;   // batch element (683*6 = 4098)
    const int ec = (e < 4095) ? e : 4095;
    const bool st = live && (e < 4096);

    if (uwid == 0) {
        // ================= LAYER-0 (producer) wave =================
        // w[q][0..3] = x-part pairs, w[q][4..8] = h-part pairs; q = i,f,g,o
        v2h w[4][9]; float bb[4];
        #pragma unroll
        for (int q = 0; q < 4; ++q) {
            const int r = q * 10 + j;
            const float sc = (q == 2) ? 2.0f * L2E : L2E;
            #pragma unroll
            for (int k = 0; k < 4; ++k)
                w[q][k] = pkh(Wih0[r*8+2*k]*sc, Wih0[r*8+2*k+1]*sc);
            #pragma unroll
            for (int k = 0; k < 5; ++k)
                w[q][4+k] = pkh(Whh0[r*10+2*k]*sc, Whh0[r*10+2*k+1]*sc);
            bb[q] = (bih0[r] + bhh0[r]) * sc;
        }
        v2h hv[5];
        #pragma unroll
        for (int k = 0; k < 5; ++k) hv[k] = pkh(hid[ec*10+2*k], hid[ec*10+2*k+1]);
        float cc = cel[ec * 10 + j];
        float hj = 0.0f;

        __fp16* const wrow = &h0buf[0][g][0];   // slot stride 96 halves

        const float4* __restrict__ xp4 = reinterpret_cast<const float4*>(x + (size_t)ec * 4096);
        float4 xa[2], xb[2], xc[2], xd[2];      // x[t] at xp4[2t], xp4[2t+1]
        xa[0]=xp4[0]; xa[1]=xp4[1];  xb[0]=xp4[2]; xb[1]=xp4[3];
        xc[0]=xp4[4]; xc[1]=xp4[5];  xd[0]=xp4[6]; xd[1]=xp4[7];

// step: slot S (= step&15), buffer XB (= step&3), refill x from xr[ROFF]
#define L0STEP(S, XB, ROFF, DO_REF)                                          \
        {                                                                    \
            v2h x0=pkh(XB[0].x,XB[0].y), x1=pkh(XB[0].z,XB[0].w);            \
            v2h x2=pkh(XB[1].x,XB[1].y), x3=pkh(XB[1].z,XB[1].w);            \
            if (DO_REF) { XB[0]=xr[ROFF]; XB[1]=xr[(ROFF)+1]; }              \
            float aI=bb[0], aF=bb[1], aG=bb[2], aO=bb[3];                    \
            DOT2(aI,w[0][0],x0); DOT2(aF,w[1][0],x0);                        \
            DOT2(aG,w[2][0],x0); DOT2(aO,w[3][0],x0);                        \
            DOT2(aI,w[0][1],x1); DOT2(aF,w[1][1],x1);                        \
            DOT2(aG,w[2][1],x1); DOT2(aO,w[3][1],x1);                        \
            DOT2(aI,w[0][2],x2); DOT2(aF,w[1][2],x2);                        \
            DOT2(aG,w[2][2],x2); DOT2(aO,w[3][2],x2);                        \
            DOT2(aI,w[0][3],x3); DOT2(aF,w[1][3],x3);                        \
            DOT2(aG,w[2][3],x3); DOT2(aO,w[3][3],x3);                        \
            _Pragma("unroll")                                                \
            for (int k = 0; k < 5; ++k) {                                    \
                DOT2(aI,w[0][4+k],hv[k]); DOT2(aF,w[1][4+k],hv[k]);          \
                DOT2(aG,w[2][4+k],hv[k]); DOT2(aO,w[3][4+k],hv[k]);          \
            }                                                                \
            float i_=SIGM(aI), f_=SIGM(aF), g_=TANHP(aG), o_=SIGM(aO);       \
            cc = fmaf(f_, cc, i_ * g_);                                      \
            hj = o_ * TANHP((2.0f*L2E) * cc);                                \
            wrow[(S)*96 + j] = (__fp16)hj;                                   \
            READROW(wrow + (S)*96, hv)                                       \
        }

        for (int it = 0; it < 31; ++it) {
            const float4* __restrict__ xr = xp4 + 32 * it;
            L0STEP(0,  xa, 8,  1)  L0STEP(1,  xb, 10, 1)
            L0STEP(2,  xc, 12, 1)  L0STEP(3,  xd, 14, 1)
            L0STEP(4,  xa, 16, 1)  L0STEP(5,  xb, 18, 1)
            L0STEP(6,  xc, 20, 1)  L0STEP(7,  xd, 22, 1)
            __syncthreads();
            L0STEP(8,  xa, 24, 1)  L0STEP(9,  xb, 26, 1)
            L0STEP(10, xc, 28, 1)  L0STEP(11, xd, 30, 1)
            L0STEP(12, xa, 32, 1)  L0STEP(13, xb, 34, 1)
            L0STEP(14, xc, 36, 1)  L0STEP(15, xd, 38, 1)
            __syncthreads();
        }
        // peeled it=31: steps 496..511 (refills stop past x[511])
        {
            const float4* __restrict__ xr = xp4 + 992;
            L0STEP(0,  xa, 8,  1)  L0STEP(1,  xb, 10, 1)
            L0STEP(2,  xc, 12, 1)  L0STEP(3,  xd, 14, 1)
            L0STEP(4,  xa, 16, 1)  L0STEP(5,  xb, 18, 1)
            L0STEP(6,  xc, 20, 1)  L0STEP(7,  xd, 22, 1)
            __syncthreads();
            L0STEP(8,  xa, 24, 1)  L0STEP(9,  xb, 26, 1)   // refill x[508],x[509]
            L0STEP(10, xc, 28, 1)  L0STEP(11, xd, 30, 1)   // refill x[510],x[511]
            L0STEP(12, xa, 0, 0)   L0STEP(13, xb, 0, 0)
            L0STEP(14, xc, 0, 0)   L0STEP(15, xd, 0, 0)
            __syncthreads();
        }
#undef L0STEP

        if (st) {
            out[4096          + e * 10 + j] = hj;   // h0_T
            out[4096 + 81920  + e * 10 + j] = cc;   // c0_T
        }

    } else {
        // ================= LAYER-1 (consumer) wave =================
        // w[q][0..4] = input(h0) pairs, w[q][5..9] = recurrent(h1) pairs
        v2h w[4][10]; float bb[4];
        #pragma unroll
        for (int q = 0; q < 4; ++q) {
            const int r = q * 10 + j;
            const float sc = (q == 2) ? 2.0f * L2E : L2E;
            #pragma unroll
            for (int k = 0; k < 5; ++k) {
                w[q][k]   = pkh(Wih1[r*10+2*k]*sc, Wih1[r*10+2*k+1]*sc);
                w[q][5+k] = pkh(Whh1[r*10+2*k]*sc, Whh1[r*10+2*k+1]*sc);
            }
            bb[q] = (bih1[r] + bhh1[r]) * sc;
        }
        v2h hv[5];
        #pragma unroll
        for (int k = 0; k < 5; ++k) hv[k] = pkh(hid[40960+ec*10+2*k], hid[40960+ec*10+2*k+1]);
        float cc = cel[40960 + ec * 10 + j];
        float hj = 0.0f;

        const __fp16* const rbase = &h0buf[0][g][0];  // slot stride 96 halves
        __fp16* const h1r = &h1buf[g][0];

#define L1STEP(S)                                                            \
        {                                                                    \
            v2h p[5];                                                        \
            READROW(rbase + (S)*96, p)                                       \
            float aI=bb[0], aF=bb[1], aG=bb[2], aO=bb[3];                    \
            _Pragma("unroll")                                                \
            for (int k = 0; k < 5; ++k) {                                    \
                DOT2(aI,w[0][5+k],hv[k]); DOT2(aF,w[1][5+k],hv[k]);          \
                DOT2(aG,w[2][5+k],hv[k]); DOT2(aO,w[3][5+k],hv[k]);          \
            }                                                                \
            _Pragma("unroll")                                                \
            for (int k = 0; k < 5; ++k) {                                    \
                DOT2(aI,w[0][k],p[k]); DOT2(aF,w[1][k],p[k]);                \
                DOT2(aG,w[2][k],p[k]); DOT2(aO,w[3][k],p[k]);                \
            }                                                                \
            float i_=SIGM(aI), f_=SIGM(aF), g_=TANHP(aG), o_=SIGM(aO);       \
            cc = fmaf(f_, cc, i_ * g_);                                      \
            hj = o_ * TANHP((2.0f*L2E) * cc);                                \
            h1r[j] = (__fp16)hj;                                             \
            READROW(h1r, hv)                                                 \
        }

        for (int it = 0; it < 32; ++it) {
            __syncthreads();
            L1STEP(0)  L1STEP(1)  L1STEP(2)  L1STEP(3)
            L1STEP(4)  L1STEP(5)  L1STEP(6)  L1STEP(7)
            __syncthreads();
            L1STEP(8)  L1STEP(9)  L1STEP(10) L1STEP(11)
            L1STEP(12) L1STEP(13) L1STEP(14) L1STEP(15)
        }
#undef L1STEP

        if (live) fcb[g][j] = hj * Wfc[j];
        if (st) {
            out[4096 + 40960  + e * 10 + j] = hj;   // h1_T
            out[4096 + 122880 + e * 10 + j] = cc;   // c1_T
        }
        if (st && j == 0) {
            float p = bfc[0];
            #pragma unroll
            for (int k = 0; k < 10; ++k) p += fcb[g][k];
            out[e] = p;
        }
    }
}

extern "C" void kernel_launch(void* const* d_in, const int* in_sizes, int n_in,
                              void* d_out, int out_size, void* d_ws, size_t ws_size,
                              hipStream_t stream) {
    const float* x    = (const float*)d_in[0];
    const float* hid  = (const float*)d_in[1];
    const float* cel  = (const float*)d_in[2];
    const float* Wih0 = (const float*)d_in[3];
    const float* Whh0 = (const float*)d_in[4];
    const float* bih0 = (const float*)d_in[5];
    const float* bhh0 = (const float*)d_in[6];
    const float* Wih1 = (const float*)d_in[7];
    const float* Whh1 = (const float*)d_in[8];
    const float* bih1 = (const float*)d_in[9];
    const float* bhh1 = (const float*)d_in[10];
    const float* Wfc  = (const float*)d_in[11];
    const float* bfc  = (const float*)d_in[12];

    // 683 blocks x 128 thr (1 L0 wave + 1 L1 wave, 6 elements/block)
    hipLaunchKernelGGL(lstm2_r13, dim3(683), dim3(128), 0, stream,
                       x, hid, cel, Wih0, Whh0, bih0, bhh0,
                       Wih1, Whh1, bih1, bhh1, Wfc, bfc,
                       (float*)d_out);
}